// Round 15
// baseline (312.226 us; speedup 1.0000x reference)
//
#include <hip/hip_runtime.h>

// Problem constants
#define NB 16
#define NS 512
#define ND 2048
#define NH 16
#define NG 4
#define NHD 128
#define NM (NB * NS)      // 8192 rows (b*s)
#define NKD (NG * NHD)    // 512
#define NKV 1024          // fused K|V row width
#define HEAD_SCALE 0.08838834764831845f

typedef _Float16 h8 __attribute__((ext_vector_type(8)));
typedef float fx4 __attribute__((ext_vector_type(4)));

// global -> LDS direct copy, 16B per lane. LDS dest is wave-uniform base + lane*16.
__device__ __forceinline__ void gload16(const void* g, void* l) {
  __builtin_amdgcn_global_load_lds(
      (__attribute__((address_space(1))) void*)(unsigned long long)g,
      (__attribute__((address_space(3))) void*)(unsigned long long)l,
      16, 0, 0);
}

// ---------------- fused prep kernel ----------------
// block ranges: [0,2048) cvt_x | [2048,3072) wtrans wq | [3072,3328) wtrans wk |
// [3328,3584) wtrans wv | [3584,4608) wtrans wo | [4608,4736) rope | [4736] bias.

__global__ void prep_kernel(const float* __restrict__ x, _Float16* __restrict__ xh,
                            const float* __restrict__ wq, _Float16* __restrict__ wqt,
                            const float* __restrict__ wk, const float* __restrict__ wv,
                            _Float16* __restrict__ wkvt,
                            const float* __restrict__ wo, _Float16* __restrict__ wot,
                            float* __restrict__ cosT, float* __restrict__ sinT,
                            const float* __restrict__ bk, const float* __restrict__ bv,
                            float* __restrict__ bkv) {
  __shared__ float t[64][65];
  const int bid = blockIdx.x, tid = threadIdx.x;
  if (bid < 2048) {
    const fx4* p = (const fx4*)x;
    h8* o = (h8*)xh;
#pragma unroll
    for (int it = 0; it < 4; ++it) {
      int i = (it * 2048 + bid) * 256 + tid;
      fx4 a = p[2 * i], b = p[2 * i + 1];
      h8 hv;
      hv[0] = (_Float16)a[0]; hv[1] = (_Float16)a[1]; hv[2] = (_Float16)a[2]; hv[3] = (_Float16)a[3];
      hv[4] = (_Float16)b[0]; hv[5] = (_Float16)b[1]; hv[6] = (_Float16)b[2]; hv[7] = (_Float16)b[3];
      o[i] = hv;
    }
    return;
  }
  int lb = bid - 2048;
  const float* src;
  _Float16* dst;
  int K, N;
  if (lb < 1024)      { src = wq; dst = wqt; K = ND; N = ND; }
  else if (lb < 1280) { lb -= 1024; src = wk; dst = wkvt; K = ND; N = NKD; }
  else if (lb < 1536) { lb -= 1280; src = wv; dst = wkvt + (size_t)NKD * ND; K = ND; N = NKD; }
  else if (lb < 2560) { lb -= 1536; src = wo; dst = wot; K = ND; N = ND; }
  else if (lb < 2688) {
    int i = (lb - 2560) * 256 + tid;
    int s = i >> 6, f = i & 63;
    float inv = exp2f(-(float)f * (13.287712379549449f / 64.0f));
    float a = (float)s * inv;
    cosT[i] = cosf(a);
    sinT[i] = sinf(a);
    return;
  } else {
#pragma unroll
    for (int it = 0; it < 4; ++it) {
      int idx = it * 256 + tid;
      bkv[idx] = (idx < NKD) ? bk[idx] : bv[idx - NKD];
    }
    return;
  }
  const int ntil = N >> 6;
  const int n0 = (lb % ntil) * 64, k0 = (lb / ntil) * 64;
#pragma unroll
  for (int it = 0; it < 16; ++it) {
    int idx = it * 256 + tid;
    int r = idx >> 6, c = idx & 63;
    t[r][c] = src[(size_t)(k0 + r) * N + n0 + c];
  }
  __syncthreads();
#pragma unroll
  for (int it = 0; it < 16; ++it) {
    int idx = it * 256 + tid;
    int r = idx >> 6, c = idx & 63;
    dst[(size_t)(n0 + r) * K + k0 + c] = (_Float16)t[c][r];
  }
}

// ---------------- merged KV post-processing ----------------
// [0,8192): K RMSNorm+RoPE in place (cols [0,512) of KVbuf).
// [8192,9216): V transpose (cols [512,1024) of KVbuf) -> Vt[b*4+g][128][512].

__global__ void kv_post_kernel(_Float16* __restrict__ kv, _Float16* __restrict__ vt,
                               const float* __restrict__ kns,
                               const float* __restrict__ cosT, const float* __restrict__ sinT) {
  __shared__ _Float16 t[64][72];
  const int bid = blockIdx.x, tid = threadIdx.x;
  if (bid < 8192) {  // K norm+rope: 4 (row,head) tasks per block
    int wid = tid >> 6, lane = tid & 63;
    int task = bid * 4 + wid;
    int row = task >> 2;
    int head = task & 3;
    _Float16* p = kv + (size_t)row * NKV + head * NHD;
    float x1 = (float)p[lane], x2 = (float)p[lane + 64];
    float ss = x1 * x1 + x2 * x2;
#pragma unroll
    for (int m = 1; m < 64; m <<= 1) ss += __shfl_xor(ss, m, 64);
    float rn = rsqrtf(ss * (1.0f / 128.0f) + 1e-6f);
    int s = row & (NS - 1);
    float c = cosT[s * 64 + lane], sn = sinT[s * 64 + lane];
    float n1 = x1 * rn * kns[lane], n2 = x2 * rn * kns[64 + lane];
    p[lane] = (_Float16)(n1 * c - n2 * sn);
    p[lane + 64] = (_Float16)(n1 * sn + n2 * c);
    return;
  }
  const int v = bid - 8192;
  const int st = v & 7, dt = (v >> 3) & 1, bg = v >> 4;
  const int b = bg >> 2, g = bg & 3;
  const _Float16* src = kv + ((size_t)(b * NS + st * 64)) * NKV + NKD + g * NHD + dt * 64;
#pragma unroll
  for (int it = 0; it < 2; ++it) {
    int idx = it * 256 + tid;
    int r = idx >> 3, c = (idx & 7) * 8;
    *(h8*)&t[r][c] = *(const h8*)(src + (size_t)r * NKV + c);
  }
  __syncthreads();
  _Float16* dst = vt + ((size_t)bg * NHD + dt * 64) * NS + st * 64;
#pragma unroll
  for (int it = 0; it < 2; ++it) {
    int idx = it * 256 + tid;
    int r = idx >> 3, c = (idx & 7) * 8;
    h8 o;
#pragma unroll
    for (int e = 0; e < 8; ++e) o[e] = t[c + e][r];
    *(h8*)(dst + (size_t)r * NS + c) = o;
  }
}

__device__ __forceinline__ void st_out(float* p, float v) { *p = v; }
__device__ __forceinline__ void st_out(_Float16* p, float v) { *p = (_Float16)v; }

// ---------------- GEMM 256x256, fine-interleaved 4-phase (r8-verified) ------------
// Frozen at r8 structure: 75.5us, 0 bank conflicts, MfmaUtil 36%.

template <typename OT>
__global__ __launch_bounds__(512, 2) void gemm256_kernel(
    const _Float16* __restrict__ A, const _Float16* __restrict__ Bt,
    const float* __restrict__ bias, OT* __restrict__ C, int N, int K) {
  __shared__ alignas(16) _Float16 As[2][2][256 * 32];
  __shared__ alignas(16) _Float16 Bs[2][2][256 * 32];
  const int tid = threadIdx.x;
  const int lane = tid & 63, w = tid >> 6;
  const int wr = w >> 2, wc = w & 3;
  const int la = lane & 15, lq = lane >> 4;
  const int lin = (blockIdx.x & 7) * 32 + (blockIdx.x >> 3);
  const int nbx = N >> 8;
  const int by = lin / nbx, bx = lin % nbx;
  const int bm = by * 256, bn = bx * 256;
  const int NT = K >> 6;

  fx4 acc[8][4] = {};

  {
    const _Float16* Ag = A + (size_t)bm * K;
    const _Float16* Bg = Bt + (size_t)bn * K;
#pragma unroll
    for (int sh = 0; sh < 2; ++sh) {
#pragma unroll
      for (int i = 0; i < 2; ++i) {
        int cb = i * 512 + w * 64;
        int s = cb + lane;
        int r = s >> 2, c = s & 3;
        gload16(Ag + (size_t)r * K + sh * 32 + ((c ^ ((r >> 1) & 3)) << 3), &As[0][sh][cb * 8]);
      }
#pragma unroll
      for (int i = 0; i < 2; ++i) {
        int cb = i * 512 + w * 64;
        int s = cb + lane;
        int r = s >> 2, c = s & 3;
        gload16(Bg + (size_t)r * K + sh * 32 + ((c ^ ((r >> 1) & 3)) << 3), &Bs[0][sh][cb * 8]);
      }
    }
  }
  asm volatile("s_waitcnt vmcnt(4)" ::: "memory");
  __builtin_amdgcn_s_barrier();

  for (int kt = 0; kt < NT; ++kt) {
    const int cur = kt & 1;
    const int nxt = cur ^ 1;
    const bool more = (kt + 1 < NT);
    const _Float16* Ag = A + (size_t)bm * K + (kt + 1) * 64;
    const _Float16* Bg = Bt + (size_t)bn * K + (kt + 1) * 64;
    h8 bf[4];
#pragma unroll
    for (int ph = 0; ph < 4; ++ph) {
      const int kh = ph >> 1, g = ph & 1;
      h8 af[4];
#pragma unroll
      for (int mi = 0; mi < 4; ++mi) {
        int row = wr * 128 + (g * 4 + mi) * 16 + la;
        af[mi] = *(const h8*)&As[cur][kh][row * 32 + ((lq ^ ((row >> 1) & 3)) << 3)];
      }
      if (g == 0) {
#pragma unroll
        for (int ni = 0; ni < 4; ++ni) {
          int row = wc * 64 + ni * 16 + la;
          bf[ni] = *(const h8*)&Bs[cur][kh][row * 32 + ((lq ^ ((row >> 1) & 3)) << 3)];
        }
      }
      if (more) {
        const int sh = ph >> 1;
        const _Float16* Sg = (ph & 1) ? Bg : Ag;
        _Float16* Ld = (ph & 1) ? &Bs[nxt][sh][0] : &As[nxt][sh][0];
#pragma unroll
        for (int i = 0; i < 2; ++i) {
          int cb = i * 512 + w * 64;
          int s = cb + lane;
          int r = s >> 2, c = s & 3;
          gload16(Sg + (size_t)r * K + sh * 32 + ((c ^ ((r >> 1) & 3)) << 3), Ld + cb * 8);
        }
      }
      if (ph == 1 || ph == 3) {
        if (more) asm volatile("s_waitcnt vmcnt(4)" ::: "memory");
        else      asm volatile("s_waitcnt vmcnt(0)" ::: "memory");
      }
      __builtin_amdgcn_s_barrier();
      asm volatile("s_waitcnt lgkmcnt(0)" ::: "memory");
      __builtin_amdgcn_sched_barrier(0);
      __builtin_amdgcn_s_setprio(1);
#pragma unroll
      for (int mi = 0; mi < 4; ++mi)
#pragma unroll
        for (int ni = 0; ni < 4; ++ni)
          acc[g * 4 + mi][ni] = __builtin_amdgcn_mfma_f32_16x16x32_f16(
              af[mi], bf[ni], acc[g * 4 + mi][ni], 0, 0, 0);
      __builtin_amdgcn_s_setprio(0);
      __builtin_amdgcn_sched_barrier(0);
      __builtin_amdgcn_s_barrier();
    }
  }
#pragma unroll
  for (int mi = 0; mi < 8; ++mi) {
    int row0 = bm + wr * 128 + mi * 16 + lq * 4;
#pragma unroll
    for (int ni = 0; ni < 4; ++ni) {
      int col = bn + wc * 64 + ni * 16 + la;
      float bvv = bias[col];
#pragma unroll
      for (int r = 0; r < 4; ++r)
        st_out(&C[(size_t)(row0 + r) * N + col], acc[mi][ni][r] + bvv);
    }
  }
}

// ---------------- GEMM 256x128 — same r8 skeleton, BN=128 (KV projection) ---------
// 8 waves (2M x 4N): wave tile 128x32. Per tile: 6 loads (A=4, B=2).
// vmcnt(3) at ph1/ph3: each seals the half consumed two phases later.
// FIX (r14 bug): stageB's LDS dest must be PER-WAVE (base + w*64 chunks) —
// gload_lds writes wave-uniform-base + lane*16, so all 8 waves were DMAing
// into the same 1KB. Each wave now owns chunks [64w, 64w+64).

__global__ __launch_bounds__(512, 2) void gemm256n128_kernel(
    const _Float16* __restrict__ A, const _Float16* __restrict__ Bt,
    const float* __restrict__ bias, _Float16* __restrict__ C, int N, int K) {
  __shared__ alignas(16) _Float16 As[2][2][256 * 32];
  __shared__ alignas(16) _Float16 Bs[2][2][128 * 32];
  const int tid = threadIdx.x;
  const int lane = tid & 63, w = tid >> 6;
  const int wr = w >> 2, wc = w & 3;
  const int la = lane & 15, lq = lane >> 4;
  const int lin = (blockIdx.x & 7) * 32 + (blockIdx.x >> 3);
  const int nbx = N >> 7;  // 8
  const int by = lin / nbx, bx = lin % nbx;
  const int bm = by * 256, bn = bx * 128;
  const int NT = K >> 6;

  fx4 acc[8][2] = {};

  auto stageA = [&](int buf, int kt, int sh) {
    const _Float16* Ag = A + (size_t)bm * K + kt * 64;
#pragma unroll
    for (int i = 0; i < 2; ++i) {
      int cb = i * 512 + w * 64;
      int s = cb + lane;
      int r = s >> 2, c = s & 3;
      gload16(Ag + (size_t)r * K + sh * 32 + ((c ^ ((r >> 1) & 3)) << 3), &As[buf][sh][cb * 8]);
    }
  };
  auto stageB = [&](int buf, int kt, int sh) {
    const _Float16* Bg = Bt + (size_t)bn * K + kt * 64;
    int s = w * 64 + lane;  // 512 chunks = 128 rows x 4
    int r = s >> 2, c = s & 3;
    gload16(Bg + (size_t)r * K + sh * 32 + ((c ^ ((r >> 1) & 3)) << 3),
            &Bs[buf][sh][(w * 64) * 8]);  // per-wave LDS base (the fix)
  };

  // prologue: A0(2), B0(1), A1(2), B1(1); vmcnt(3) seals kh0 (A0+B0).
  stageA(0, 0, 0);
  stageB(0, 0, 0);
  stageA(0, 0, 1);
  stageB(0, 0, 1);
  asm volatile("s_waitcnt vmcnt(3)" ::: "memory");
  __builtin_amdgcn_s_barrier();

  for (int kt = 0; kt < NT; ++kt) {
    const int cur = kt & 1;
    const int nxt = cur ^ 1;
    const bool more = (kt + 1 < NT);
    h8 bf[2];
#pragma unroll
    for (int ph = 0; ph < 4; ++ph) {
      const int kh = ph >> 1, g = ph & 1;
      h8 af[4];
#pragma unroll
      for (int mi = 0; mi < 4; ++mi) {
        int row = wr * 128 + (g * 4 + mi) * 16 + la;
        af[mi] = *(const h8*)&As[cur][kh][row * 32 + ((lq ^ ((row >> 1) & 3)) << 3)];
      }
      if (g == 0) {
#pragma unroll
        for (int ni = 0; ni < 2; ++ni) {
          int row = wc * 32 + ni * 16 + la;
          bf[ni] = *(const h8*)&Bs[cur][kh][row * 32 + ((lq ^ ((row >> 1) & 3)) << 3)];
        }
      }
      if (more) {
        const int sh = ph >> 1;
        if (ph & 1) stageB(nxt, kt + 1, sh);
        else        stageA(nxt, kt + 1, sh);
      }
      if (ph == 1 || ph == 3) {
        if (more) asm volatile("s_waitcnt vmcnt(3)" ::: "memory");
        else      asm volatile("s_waitcnt vmcnt(0)" ::: "memory");
      }
      __builtin_amdgcn_s_barrier();
      asm volatile("s_waitcnt lgkmcnt(0)" ::: "memory");
      __builtin_amdgcn_sched_barrier(0);
      __builtin_amdgcn_s_setprio(1);
#pragma unroll
      for (int mi = 0; mi < 4; ++mi)
#pragma unroll
        for (int ni = 0; ni < 2; ++ni)
          acc[g * 4 + mi][ni] = __builtin_amdgcn_mfma_f32_16x16x32_f16(
              af[mi], bf[ni], acc[g * 4 + mi][ni], 0, 0, 0);
      __builtin_amdgcn_s_setprio(0);
      __builtin_amdgcn_sched_barrier(0);
      __builtin_amdgcn_s_barrier();
    }
  }
#pragma unroll
  for (int mi = 0; mi < 8; ++mi) {
    int row0 = bm + wr * 128 + mi * 16 + lq * 4;
#pragma unroll
    for (int ni = 0; ni < 2; ++ni) {
      int col = bn + wc * 32 + ni * 16 + la;
      float bvv = bias[col];
#pragma unroll
      for (int r = 0; r < 4; ++r)
        C[(size_t)(row0 + r) * N + col] = (_Float16)(acc[mi][ni][r] + bvv);
    }
  }
}

// ---------------- flash attention (r8-proven schedule, fused Q norm/rope,
//                   direct C-store, T13 defer-max, masked-subtile skip) --------

__global__ __launch_bounds__(512, 4) void attn_kernel(
    const _Float16* __restrict__ Q, const _Float16* __restrict__ KV,
    const _Float16* __restrict__ Vt, _Float16* __restrict__ ctx,
    const float* __restrict__ qns, const float* __restrict__ cosT,
    const float* __restrict__ sinT) {
  __shared__ alignas(16) _Float16 Ks[2][64 * 128];
  __shared__ alignas(16) _Float16 Vs[2][128 * 64];
  __shared__ alignas(16) _Float16 Ps[8][16 * 64];

  const int bid = blockIdx.x;
  const int logical = (bid & 7) * 64 + (bid >> 3);
  const int b = logical >> 5;
  const int g = (logical >> 3) & 3;
  const int jp = logical & 7;
  const int j1 = jp, j2 = 15 - jp;

  const int tid = threadIdx.x;
  const int lane = tid & 63, w = tid >> 6;
  const int la = lane & 15, lq = lane >> 4;
  const int h = g * 4 + (w & 3);
  const int rh = w >> 2;

  const _Float16* Vg = Vt + (size_t)(b * NG + g) * NHD * NS;

  auto stage = [&](int buf, int kt) {
    const _Float16* Kg = KV + ((size_t)(b * NS + kt * 64)) * NKV + g * NHD;
#pragma unroll
    for (int it = 0; it < 2; ++it) {
      int cb = it * 512 + w * 64;
      int s = cb + lane;
      int rr = s >> 4, c = s & 15;
      gload16(Kg + (size_t)rr * NKV + ((c ^ (rr & 7)) * 8), &Ks[buf][cb * 8]);
    }
#pragma unroll
    for (int it = 0; it < 2; ++it) {
      int cb = it * 512 + w * 64;
      int s = cb + lane;
      int rr = s >> 3, c = s & 7;
      gload16(Vg + (size_t)rr * NS + kt * 64 + ((c ^ (rr & 7)) * 8), &Vs[buf][cb * 8]);
    }
  };

  const int nt1 = ((j1 * 32 + 31) >> 6) + 1;
  const int nt2 = ((j2 * 32 + 31) >> 6) + 1;
  const int ntotal = nt1 + nt2;  // == 9

  h8 qf[4];
  fx4 oacc[8];
  float mrun[4], lrun[4];

  stage(0, 0);
  int cur = 0;
  for (int t = 0; t < ntotal; ++t) {
    const bool inA = t < nt1;
    const int j = inA ? j1 : j2;
    const int kt = inA ? t : t - nt1;
    const int ntj = inA ? nt1 : nt2;
    __syncthreads();  // drains vmcnt(0): buf[cur] staged; all waves done with buf[cur^1]
    if (t + 1 < ntotal) {
      int nkt = (t + 1 < nt1) ? (t + 1) : (t + 1 - nt1);
      stage(cur ^ 1, nkt);
    }
    if (kt == 0) {  // new q-tile: load raw Q row, fused RMSNorm+RoPE+HEAD_SCALE
      const int qrow = j * 32 + rh * 16 + la;
      const _Float16* Qg = Q + ((size_t)(b * NS + qrow)) * ND + h * NHD + lq * 8;
      float xq[4][8];
      float ss = 0.f;
#pragma unroll
      for (int kc = 0; kc < 4; ++kc) {
        h8 v = *(const h8*)(Qg + kc * 32);
#pragma unroll
        for (int e = 0; e < 8; ++e) { xq[kc][e] = (float)v[e]; ss += xq[kc][e] * xq[kc][e]; }
      }
      ss += __shfl_xor(ss, 16, 64);
      ss += __shfl_xor(ss, 32, 64);
      float rn = rsqrtf(ss * (1.0f / 128.0f) + 1e-6f);
#pragma unroll
      for (int kc = 0; kc < 2; ++kc) {
        const float* s1p = qns + kc * 32 + lq * 8;
        const float* s2p = qns + (kc + 2) * 32 + lq * 8;
        const float* ctp = cosT + qrow * 64 + kc * 32 + lq * 8;
        const float* stp = sinT + qrow * 64 + kc * 32 + lq * 8;
        fx4 s1a = *(const fx4*)s1p, s1b = *(const fx4*)(s1p + 4);
        fx4 s2a = *(const fx4*)s2p, s2b = *(const fx4*)(s2p + 4);
        fx4 ca = *(const fx4*)ctp, cb2 = *(const fx4*)(ctp + 4);
        fx4 sa = *(const fx4*)stp, sb = *(const fx4*)(stp + 4);
#pragma unroll
        for (int e = 0; e < 8; ++e) {
          float sc1 = (e < 4) ? s1a[e & 3] : s1b[e & 3];
          float sc2 = (e < 4) ? s2a[e & 3] : s2b[e & 3];
          float cc = (e < 4) ? ca[e & 3] : cb2[e & 3];
          float sn = (e < 4) ? sa[e & 3] : sb[e & 3];
          float n1 = xq[kc][e] * rn * sc1;
          float n2 = xq[kc + 2][e] * rn * sc2;
          qf[kc][e] = (_Float16)((n1 * cc - n2 * sn) * HEAD_SCALE);
          qf[kc + 2][e] = (_Float16)((n1 * sn + n2 * cc) * HEAD_SCALE);
        }
      }
#pragma unroll
      for (int f = 0; f < 8; ++f) oacc[f] = fx4{0.f, 0.f, 0.f, 0.f};
#pragma unroll
      for (int r = 0; r < 4; ++r) { mrun[r] = -1e30f; lrun[r] = 0.f; }
    }

    const bool maskT = (kt == ntj - 1);
    // On diagonal tiles of even j, kv-subtiles n>=2 are fully masked
    // (rows occupy the lower 32 of the 64-wide tile). Block-uniform.
    const int nlim = maskT ? ((((j * 32 + 31) & 63) >> 4) + 1) : 4;

    // QK^T: 16 q-rows x 64 kv (only live subtiles)
    fx4 sc[4] = {};
    __builtin_amdgcn_s_setprio(1);
#pragma unroll
    for (int n = 0; n < 4; ++n) {
      if (n < nlim) {
        int row = n * 16 + la;
#pragma unroll
        for (int kc = 0; kc < 4; ++kc) {
          h8 bk = *(const h8*)&Ks[cur][row * 128 + (((kc * 4 + lq) ^ (la & 7)) * 8)];
          sc[n] = __builtin_amdgcn_mfma_f32_16x16x32_f16(qf[kc], bk, sc[n], 0, 0, 0);
        }
      }
    }
    __builtin_amdgcn_s_setprio(0);

    const int qrow0 = j * 32 + rh * 16 + lq * 4;
    float pv[4][4];
    float rm[4] = {-1e30f, -1e30f, -1e30f, -1e30f};
#pragma unroll
    for (int n = 0; n < 4; ++n) {
      if (n < nlim) {
        int kv = kt * 64 + n * 16 + la;
#pragma unroll
        for (int r = 0; r < 4; ++r) {
          float sv = sc[n][r] * HEAD_SCALE;
          sv = (maskT && kv > qrow0 + r) ? -1e30f : sv;
          pv[n][r] = sv;
          rm[r] = fmaxf(rm[r], sv);
        }
      }
    }
#pragma unroll
    for (int r = 0; r < 4; ++r)
#pragma unroll
      for (int m = 1; m < 16; m <<= 1) rm[r] = fmaxf(rm[r], __shfl_xor(rm[r], m, 64));
    // T13 defer-max: skip O-rescale when tile-max within 8 of running max.
    bool defer = (rm[0] - mrun[0] <= 8.f) && (rm[1] - mrun[1] <= 8.f) &&
                 (rm[2] - mrun[2] <= 8.f) && (rm[3] - mrun[3] <= 8.f);
    if (!__all(defer)) {
#pragma unroll
      for (int r = 0; r < 4; ++r) {
        float mn = fmaxf(mrun[r], rm[r]);
        float corr = __expf(mrun[r] - mn);
        mrun[r] = mn;
        lrun[r] *= corr;
#pragma unroll
        for (int f = 0; f < 8; ++f) oacc[f][r] *= corr;
      }
    }
    float rs[4] = {0.f, 0.f, 0.f, 0.f};
#pragma unroll
    for (int n = 0; n < 4; ++n) {
      if (n < nlim) {
#pragma unroll
        for (int r = 0; r < 4; ++r) {
          float e = __expf(pv[n][r] - mrun[r]);
          pv[n][r] = e;
          rs[r] += e;
        }
      } else {
#pragma unroll
        for (int r = 0; r < 4; ++r) pv[n][r] = 0.f;
      }
    }
#pragma unroll
    for (int r = 0; r < 4; ++r) {
#pragma unroll
      for (int m = 1; m < 16; m <<= 1) rs[r] += __shfl_xor(rs[r], m, 64);
      lrun[r] += rs[r];
    }

    // P (C-layout) -> LDS (swizzled) -> reload in A-layout (wave-local)
#pragma unroll
    for (int n = 0; n < 4; ++n)
#pragma unroll
      for (int r = 0; r < 4; ++r) {
        int row = lq * 4 + r;
        int chsw = (n * 2 + (la >> 3)) ^ (row & 7);
        Ps[w][row * 64 + chsw * 8 + (la & 7)] = (_Float16)pv[n][r];
      }
    asm volatile("s_waitcnt lgkmcnt(0)" ::: "memory");
    __builtin_amdgcn_sched_barrier(0);
    h8 pf[2];
#pragma unroll
    for (int ks = 0; ks < 2; ++ks)
      pf[ks] = *(const h8*)&Ps[w][la * 64 + (((ks * 4 + lq) ^ (la & 7)) * 8)];

    // PV
    __builtin_amdgcn_s_setprio(1);
#pragma unroll
    for (int f = 0; f < 8; ++f) {
      int row = f * 16 + la;
#pragma unroll
      for (int ks = 0; ks < 2; ++ks) {
        h8 bv = *(const h8*)&Vs[cur][row * 64 + (((ks * 4 + lq) ^ (la & 7)) * 8)];
        oacc[f] = __builtin_amdgcn_mfma_f32_16x16x32_f16(pf[ks], bv, oacc[f], 0, 0, 0);
      }
    }
    __builtin_amdgcn_s_setprio(0);

    if (maskT) {  // last tile of this q-tile: direct store (r11-verified)
      _Float16* Cg = ctx + ((size_t)(b * NS + qrow0)) * ND + h * NHD + la;
      float inv_l[4];
#pragma unroll
      for (int r = 0; r < 4; ++r) inv_l[r] = 1.0f / lrun[r];
#pragma unroll
      for (int f = 0; f < 8; ++f)
#pragma unroll
        for (int r = 0; r < 4; ++r)
          Cg[(size_t)r * ND + f * 16] = (_Float16)(oacc[f][r] * inv_l[r]);
    }
    cur ^= 1;
  }
}

// ---------------- launch ----------------

extern "C" void kernel_launch(void* const* d_in, const int* in_sizes, int n_in,
                              void* d_out, int out_size, void* d_ws, size_t ws_size,
                              hipStream_t stream) {
  (void)in_sizes; (void)n_in; (void)out_size; (void)ws_size;
  const float* x = (const float*)d_in[0];
  const float* wq = (const float*)d_in[1];
  const float* bq = (const float*)d_in[2];
  const float* wk = (const float*)d_in[3];
  const float* bk = (const float*)d_in[4];
  const float* wv = (const float*)d_in[5];
  const float* bv = (const float*)d_in[6];
  const float* wo = (const float*)d_in[7];
  const float* bo = (const float*)d_in[8];
  const float* qns = (const float*)d_in[9];
  const float* kns = (const float*)d_in[10];

  char* ws = (char*)d_ws;
  size_t off = 0;
  _Float16* xh = (_Float16*)(ws + off); off += (size_t)NM * ND * 2;       // 32MB
  _Float16* wqt = (_Float16*)(ws + off); off += (size_t)ND * ND * 2;      // 8MB
  _Float16* wkvt = (_Float16*)(ws + off); off += (size_t)NKV * ND * 2;    // 4MB
  _Float16* wot = (_Float16*)(ws + off); off += (size_t)ND * ND * 2;      // 8MB
  _Float16* Qb = (_Float16*)(ws + off); off += (size_t)NM * ND * 2;       // 32MB
  _Float16* KVbuf = (_Float16*)(ws + off); off += (size_t)NM * NKV * 2;   // 16MB
  float* cosT = (float*)(ws + off); off += (size_t)NS * 64 * 4;
  float* sinT = (float*)(ws + off); off += (size_t)NS * 64 * 4;
  float* bkv = (float*)(ws + off); off += (size_t)NKV * 4;
  _Float16* ctx = xh;            // xh dead after KV GEMM; reuse
  _Float16* Vtg = wqt;           // wqt dead after Q GEMM; reuse

  prep_kernel<<<dim3(4737), 256, 0, stream>>>(x, xh, wq, wqt, wk, wv, wkvt, wo, wot,
                                              cosT, sinT, bk, bv, bkv);

  gemm256_kernel<_Float16><<<dim3(256), dim3(512), 0, stream>>>(xh, wqt, bq, Qb, ND, ND);
  gemm256n128_kernel<<<dim3(256), dim3(512), 0, stream>>>(xh, wkvt, bkv, KVbuf, NKV, ND);

  kv_post_kernel<<<dim3(9216), 256, 0, stream>>>(KVbuf, Vtg, kns, cosT, sinT);

  attn_kernel<<<dim3(512), dim3(512), 0, stream>>>(Qb, KVbuf, Vtg, ctx, qns, cosT, sinT);

  gemm256_kernel<float><<<dim3(256), dim3(512), 0, stream>>>(ctx, wot, bo, (float*)d_out, ND, ND);
}

// Round 16
// 293.942 us; speedup vs baseline: 1.0622x; 1.0622x over previous
//
#include <hip/hip_runtime.h>

// Problem constants
#define NB 16
#define NS 512
#define ND 2048
#define NH 16
#define NG 4
#define NHD 128
#define NM (NB * NS)      // 8192 rows (b*s)
#define NKD (NG * NHD)    // 512
#define NKV 1024          // fused K|V row width
#define HEAD_SCALE 0.08838834764831845f

typedef _Float16 h8 __attribute__((ext_vector_type(8)));
typedef float fx4 __attribute__((ext_vector_type(4)));

// global -> LDS direct copy, 16B per lane. LDS dest is wave-uniform base + lane*16.
__device__ __forceinline__ void gload16(const void* g, void* l) {
  __builtin_amdgcn_global_load_lds(
      (__attribute__((address_space(1))) void*)(unsigned long long)g,
      (__attribute__((address_space(3))) void*)(unsigned long long)l,
      16, 0, 0);
}

// ---------------- fused prep kernel ----------------
// block ranges: [0,2048) cvt_x | [2048,3072) wtrans wq | [3072,3328) wtrans wk |
// [3328,3584) wtrans wv | [3584,4608) wtrans wo | [4608,4736) rope | [4736] bias.

__global__ void prep_kernel(const float* __restrict__ x, _Float16* __restrict__ xh,
                            const float* __restrict__ wq, _Float16* __restrict__ wqt,
                            const float* __restrict__ wk, const float* __restrict__ wv,
                            _Float16* __restrict__ wkvt,
                            const float* __restrict__ wo, _Float16* __restrict__ wot,
                            float* __restrict__ cosT, float* __restrict__ sinT,
                            const float* __restrict__ bk, const float* __restrict__ bv,
                            float* __restrict__ bkv) {
  __shared__ float t[64][65];
  const int bid = blockIdx.x, tid = threadIdx.x;
  if (bid < 2048) {
    const fx4* p = (const fx4*)x;
    h8* o = (h8*)xh;
#pragma unroll
    for (int it = 0; it < 4; ++it) {
      int i = (it * 2048 + bid) * 256 + tid;
      fx4 a = p[2 * i], b = p[2 * i + 1];
      h8 hv;
      hv[0] = (_Float16)a[0]; hv[1] = (_Float16)a[1]; hv[2] = (_Float16)a[2]; hv[3] = (_Float16)a[3];
      hv[4] = (_Float16)b[0]; hv[5] = (_Float16)b[1]; hv[6] = (_Float16)b[2]; hv[7] = (_Float16)b[3];
      o[i] = hv;
    }
    return;
  }
  int lb = bid - 2048;
  const float* src;
  _Float16* dst;
  int K, N;
  if (lb < 1024)      { src = wq; dst = wqt; K = ND; N = ND; }
  else if (lb < 1280) { lb -= 1024; src = wk; dst = wkvt; K = ND; N = NKD; }
  else if (lb < 1536) { lb -= 1280; src = wv; dst = wkvt + (size_t)NKD * ND; K = ND; N = NKD; }
  else if (lb < 2560) { lb -= 1536; src = wo; dst = wot; K = ND; N = ND; }
  else if (lb < 2688) {
    int i = (lb - 2560) * 256 + tid;
    int s = i >> 6, f = i & 63;
    float inv = exp2f(-(float)f * (13.287712379549449f / 64.0f));
    float a = (float)s * inv;
    cosT[i] = cosf(a);
    sinT[i] = sinf(a);
    return;
  } else {
#pragma unroll
    for (int it = 0; it < 4; ++it) {
      int idx = it * 256 + tid;
      bkv[idx] = (idx < NKD) ? bk[idx] : bv[idx - NKD];
    }
    return;
  }
  const int ntil = N >> 6;
  const int n0 = (lb % ntil) * 64, k0 = (lb / ntil) * 64;
#pragma unroll
  for (int it = 0; it < 16; ++it) {
    int idx = it * 256 + tid;
    int r = idx >> 6, c = idx & 63;
    t[r][c] = src[(size_t)(k0 + r) * N + n0 + c];
  }
  __syncthreads();
#pragma unroll
  for (int it = 0; it < 16; ++it) {
    int idx = it * 256 + tid;
    int r = idx >> 6, c = idx & 63;
    dst[(size_t)(n0 + r) * K + k0 + c] = (_Float16)t[c][r];
  }
}

// ---------------- merged KV post-processing ----------------
// [0,8192): K RMSNorm+RoPE in place (cols [0,512) of KVbuf).
// [8192,9216): V transpose (cols [512,1024) of KVbuf) -> Vt[b*4+g][128][512].

__global__ void kv_post_kernel(_Float16* __restrict__ kv, _Float16* __restrict__ vt,
                               const float* __restrict__ kns,
                               const float* __restrict__ cosT, const float* __restrict__ sinT) {
  __shared__ _Float16 t[64][72];
  const int bid = blockIdx.x, tid = threadIdx.x;
  if (bid < 8192) {  // K norm+rope: 4 (row,head) tasks per block
    int wid = tid >> 6, lane = tid & 63;
    int task = bid * 4 + wid;
    int row = task >> 2;
    int head = task & 3;
    _Float16* p = kv + (size_t)row * NKV + head * NHD;
    float x1 = (float)p[lane], x2 = (float)p[lane + 64];
    float ss = x1 * x1 + x2 * x2;
#pragma unroll
    for (int m = 1; m < 64; m <<= 1) ss += __shfl_xor(ss, m, 64);
    float rn = rsqrtf(ss * (1.0f / 128.0f) + 1e-6f);
    int s = row & (NS - 1);
    float c = cosT[s * 64 + lane], sn = sinT[s * 64 + lane];
    float n1 = x1 * rn * kns[lane], n2 = x2 * rn * kns[64 + lane];
    p[lane] = (_Float16)(n1 * c - n2 * sn);
    p[lane + 64] = (_Float16)(n1 * sn + n2 * c);
    return;
  }
  const int v = bid - 8192;
  const int st = v & 7, dt = (v >> 3) & 1, bg = v >> 4;
  const int b = bg >> 2, g = bg & 3;
  const _Float16* src = kv + ((size_t)(b * NS + st * 64)) * NKV + NKD + g * NHD + dt * 64;
#pragma unroll
  for (int it = 0; it < 2; ++it) {
    int idx = it * 256 + tid;
    int r = idx >> 3, c = (idx & 7) * 8;
    *(h8*)&t[r][c] = *(const h8*)(src + (size_t)r * NKV + c);
  }
  __syncthreads();
  _Float16* dst = vt + ((size_t)bg * NHD + dt * 64) * NS + st * 64;
#pragma unroll
  for (int it = 0; it < 2; ++it) {
    int idx = it * 256 + tid;
    int r = idx >> 3, c = (idx & 7) * 8;
    h8 o;
#pragma unroll
    for (int e = 0; e < 8; ++e) o[e] = t[c + e][r];
    *(h8*)(dst + (size_t)r * NS + c) = o;
  }
}

__device__ __forceinline__ void st_out(float* p, float v) { *p = v; }
__device__ __forceinline__ void st_out(_Float16* p, float v) { *p = (_Float16)v; }

// ---------------- GEMM 256x256, fine-interleaved 4-phase (r8-verified) ------------
// Frozen at r8 structure: 75.5us, 0 bank conflicts, MfmaUtil 36%.

template <typename OT>
__global__ __launch_bounds__(512, 2) void gemm256_kernel(
    const _Float16* __restrict__ A, const _Float16* __restrict__ Bt,
    const float* __restrict__ bias, OT* __restrict__ C, int N, int K) {
  __shared__ alignas(16) _Float16 As[2][2][256 * 32];
  __shared__ alignas(16) _Float16 Bs[2][2][256 * 32];
  const int tid = threadIdx.x;
  const int lane = tid & 63, w = tid >> 6;
  const int wr = w >> 2, wc = w & 3;
  const int la = lane & 15, lq = lane >> 4;
  const int lin = (blockIdx.x & 7) * 32 + (blockIdx.x >> 3);
  const int nbx = N >> 8;
  const int by = lin / nbx, bx = lin % nbx;
  const int bm = by * 256, bn = bx * 256;
  const int NT = K >> 6;

  fx4 acc[8][4] = {};

  {
    const _Float16* Ag = A + (size_t)bm * K;
    const _Float16* Bg = Bt + (size_t)bn * K;
#pragma unroll
    for (int sh = 0; sh < 2; ++sh) {
#pragma unroll
      for (int i = 0; i < 2; ++i) {
        int cb = i * 512 + w * 64;
        int s = cb + lane;
        int r = s >> 2, c = s & 3;
        gload16(Ag + (size_t)r * K + sh * 32 + ((c ^ ((r >> 1) & 3)) << 3), &As[0][sh][cb * 8]);
      }
#pragma unroll
      for (int i = 0; i < 2; ++i) {
        int cb = i * 512 + w * 64;
        int s = cb + lane;
        int r = s >> 2, c = s & 3;
        gload16(Bg + (size_t)r * K + sh * 32 + ((c ^ ((r >> 1) & 3)) << 3), &Bs[0][sh][cb * 8]);
      }
    }
  }
  asm volatile("s_waitcnt vmcnt(4)" ::: "memory");
  __builtin_amdgcn_s_barrier();

  for (int kt = 0; kt < NT; ++kt) {
    const int cur = kt & 1;
    const int nxt = cur ^ 1;
    const bool more = (kt + 1 < NT);
    const _Float16* Ag = A + (size_t)bm * K + (kt + 1) * 64;
    const _Float16* Bg = Bt + (size_t)bn * K + (kt + 1) * 64;
    h8 bf[4];
#pragma unroll
    for (int ph = 0; ph < 4; ++ph) {
      const int kh = ph >> 1, g = ph & 1;
      h8 af[4];
#pragma unroll
      for (int mi = 0; mi < 4; ++mi) {
        int row = wr * 128 + (g * 4 + mi) * 16 + la;
        af[mi] = *(const h8*)&As[cur][kh][row * 32 + ((lq ^ ((row >> 1) & 3)) << 3)];
      }
      if (g == 0) {
#pragma unroll
        for (int ni = 0; ni < 4; ++ni) {
          int row = wc * 64 + ni * 16 + la;
          bf[ni] = *(const h8*)&Bs[cur][kh][row * 32 + ((lq ^ ((row >> 1) & 3)) << 3)];
        }
      }
      if (more) {
        const int sh = ph >> 1;
        const _Float16* Sg = (ph & 1) ? Bg : Ag;
        _Float16* Ld = (ph & 1) ? &Bs[nxt][sh][0] : &As[nxt][sh][0];
#pragma unroll
        for (int i = 0; i < 2; ++i) {
          int cb = i * 512 + w * 64;
          int s = cb + lane;
          int r = s >> 2, c = s & 3;
          gload16(Sg + (size_t)r * K + sh * 32 + ((c ^ ((r >> 1) & 3)) << 3), Ld + cb * 8);
        }
      }
      if (ph == 1 || ph == 3) {
        if (more) asm volatile("s_waitcnt vmcnt(4)" ::: "memory");
        else      asm volatile("s_waitcnt vmcnt(0)" ::: "memory");
      }
      __builtin_amdgcn_s_barrier();
      asm volatile("s_waitcnt lgkmcnt(0)" ::: "memory");
      __builtin_amdgcn_sched_barrier(0);
      __builtin_amdgcn_s_setprio(1);
#pragma unroll
      for (int mi = 0; mi < 4; ++mi)
#pragma unroll
        for (int ni = 0; ni < 4; ++ni)
          acc[g * 4 + mi][ni] = __builtin_amdgcn_mfma_f32_16x16x32_f16(
              af[mi], bf[ni], acc[g * 4 + mi][ni], 0, 0, 0);
      __builtin_amdgcn_s_setprio(0);
      __builtin_amdgcn_sched_barrier(0);
      __builtin_amdgcn_s_barrier();
    }
  }
#pragma unroll
  for (int mi = 0; mi < 8; ++mi) {
    int row0 = bm + wr * 128 + mi * 16 + lq * 4;
#pragma unroll
    for (int ni = 0; ni < 4; ++ni) {
      int col = bn + wc * 64 + ni * 16 + la;
      float bvv = bias[col];
#pragma unroll
      for (int r = 0; r < 4; ++r)
        st_out(&C[(size_t)(row0 + r) * N + col], acc[mi][ni][r] + bvv);
    }
  }
}

// ---------------- GEMM 256x128 — r8 skeleton, BN=128 (KV projection, r15-verified) --

__global__ __launch_bounds__(512, 2) void gemm256n128_kernel(
    const _Float16* __restrict__ A, const _Float16* __restrict__ Bt,
    const float* __restrict__ bias, _Float16* __restrict__ C, int N, int K) {
  __shared__ alignas(16) _Float16 As[2][2][256 * 32];
  __shared__ alignas(16) _Float16 Bs[2][2][128 * 32];
  const int tid = threadIdx.x;
  const int lane = tid & 63, w = tid >> 6;
  const int wr = w >> 2, wc = w & 3;
  const int la = lane & 15, lq = lane >> 4;
  const int lin = (blockIdx.x & 7) * 32 + (blockIdx.x >> 3);
  const int nbx = N >> 7;  // 8
  const int by = lin / nbx, bx = lin % nbx;
  const int bm = by * 256, bn = bx * 128;
  const int NT = K >> 6;

  fx4 acc[8][2] = {};

  auto stageA = [&](int buf, int kt, int sh) {
    const _Float16* Ag = A + (size_t)bm * K + kt * 64;
#pragma unroll
    for (int i = 0; i < 2; ++i) {
      int cb = i * 512 + w * 64;
      int s = cb + lane;
      int r = s >> 2, c = s & 3;
      gload16(Ag + (size_t)r * K + sh * 32 + ((c ^ ((r >> 1) & 3)) << 3), &As[buf][sh][cb * 8]);
    }
  };
  auto stageB = [&](int buf, int kt, int sh) {
    const _Float16* Bg = Bt + (size_t)bn * K + kt * 64;
    int s = w * 64 + lane;  // 512 chunks = 128 rows x 4
    int r = s >> 2, c = s & 3;
    gload16(Bg + (size_t)r * K + sh * 32 + ((c ^ ((r >> 1) & 3)) << 3),
            &Bs[buf][sh][(w * 64) * 8]);  // per-wave LDS base
  };

  stageA(0, 0, 0);
  stageB(0, 0, 0);
  stageA(0, 0, 1);
  stageB(0, 0, 1);
  asm volatile("s_waitcnt vmcnt(3)" ::: "memory");
  __builtin_amdgcn_s_barrier();

  for (int kt = 0; kt < NT; ++kt) {
    const int cur = kt & 1;
    const int nxt = cur ^ 1;
    const bool more = (kt + 1 < NT);
    h8 bf[2];
#pragma unroll
    for (int ph = 0; ph < 4; ++ph) {
      const int kh = ph >> 1, g = ph & 1;
      h8 af[4];
#pragma unroll
      for (int mi = 0; mi < 4; ++mi) {
        int row = wr * 128 + (g * 4 + mi) * 16 + la;
        af[mi] = *(const h8*)&As[cur][kh][row * 32 + ((lq ^ ((row >> 1) & 3)) << 3)];
      }
      if (g == 0) {
#pragma unroll
        for (int ni = 0; ni < 2; ++ni) {
          int row = wc * 32 + ni * 16 + la;
          bf[ni] = *(const h8*)&Bs[cur][kh][row * 32 + ((lq ^ ((row >> 1) & 3)) << 3)];
        }
      }
      if (more) {
        const int sh = ph >> 1;
        if (ph & 1) stageB(nxt, kt + 1, sh);
        else        stageA(nxt, kt + 1, sh);
      }
      if (ph == 1 || ph == 3) {
        if (more) asm volatile("s_waitcnt vmcnt(3)" ::: "memory");
        else      asm volatile("s_waitcnt vmcnt(0)" ::: "memory");
      }
      __builtin_amdgcn_s_barrier();
      asm volatile("s_waitcnt lgkmcnt(0)" ::: "memory");
      __builtin_amdgcn_sched_barrier(0);
      __builtin_amdgcn_s_setprio(1);
#pragma unroll
      for (int mi = 0; mi < 4; ++mi)
#pragma unroll
        for (int ni = 0; ni < 2; ++ni)
          acc[g * 4 + mi][ni] = __builtin_amdgcn_mfma_f32_16x16x32_f16(
              af[mi], bf[ni], acc[g * 4 + mi][ni], 0, 0, 0);
      __builtin_amdgcn_s_setprio(0);
      __builtin_amdgcn_sched_barrier(0);
      __builtin_amdgcn_s_barrier();
    }
  }
#pragma unroll
  for (int mi = 0; mi < 8; ++mi) {
    int row0 = bm + wr * 128 + mi * 16 + lq * 4;
#pragma unroll
    for (int ni = 0; ni < 2; ++ni) {
      int col = bn + wc * 32 + ni * 16 + la;
      float bvv = bias[col];
#pragma unroll
      for (int r = 0; r < 4; ++r)
        C[(size_t)(row0 + r) * N + col] = (_Float16)(acc[mi][ni][r] + bvv);
    }
  }
}

// ---------------- flash attention (r13-verified body: r8 schedule, fused Q
//                   norm/rope, direct C-store, T13 defer-max; NO nlim skip) ------

__global__ __launch_bounds__(512, 4) void attn_kernel(
    const _Float16* __restrict__ Q, const _Float16* __restrict__ KV,
    const _Float16* __restrict__ Vt, _Float16* __restrict__ ctx,
    const float* __restrict__ qns, const float* __restrict__ cosT,
    const float* __restrict__ sinT) {
  __shared__ alignas(16) _Float16 Ks[2][64 * 128];
  __shared__ alignas(16) _Float16 Vs[2][128 * 64];
  __shared__ alignas(16) _Float16 Ps[8][16 * 64];

  const int bid = blockIdx.x;
  const int logical = (bid & 7) * 64 + (bid >> 3);
  const int b = logical >> 5;
  const int g = (logical >> 3) & 3;
  const int jp = logical & 7;
  const int j1 = jp, j2 = 15 - jp;

  const int tid = threadIdx.x;
  const int lane = tid & 63, w = tid >> 6;
  const int la = lane & 15, lq = lane >> 4;
  const int h = g * 4 + (w & 3);
  const int rh = w >> 2;

  const _Float16* Vg = Vt + (size_t)(b * NG + g) * NHD * NS;

  auto stage = [&](int buf, int kt) {
    const _Float16* Kg = KV + ((size_t)(b * NS + kt * 64)) * NKV + g * NHD;
#pragma unroll
    for (int it = 0; it < 2; ++it) {
      int cb = it * 512 + w * 64;
      int s = cb + lane;
      int rr = s >> 4, c = s & 15;
      gload16(Kg + (size_t)rr * NKV + ((c ^ (rr & 7)) * 8), &Ks[buf][cb * 8]);
    }
#pragma unroll
    for (int it = 0; it < 2; ++it) {
      int cb = it * 512 + w * 64;
      int s = cb + lane;
      int rr = s >> 3, c = s & 7;
      gload16(Vg + (size_t)rr * NS + kt * 64 + ((c ^ (rr & 7)) * 8), &Vs[buf][cb * 8]);
    }
  };

  const int nt1 = ((j1 * 32 + 31) >> 6) + 1;
  const int nt2 = ((j2 * 32 + 31) >> 6) + 1;
  const int ntotal = nt1 + nt2;  // == 9

  h8 qf[4];
  fx4 oacc[8];
  float mrun[4], lrun[4];

  stage(0, 0);
  int cur = 0;
  for (int t = 0; t < ntotal; ++t) {
    const bool inA = t < nt1;
    const int j = inA ? j1 : j2;
    const int kt = inA ? t : t - nt1;
    const int ntj = inA ? nt1 : nt2;
    __syncthreads();  // drains vmcnt(0): buf[cur] staged; all waves done with buf[cur^1]
    if (t + 1 < ntotal) {
      int nkt = (t + 1 < nt1) ? (t + 1) : (t + 1 - nt1);
      stage(cur ^ 1, nkt);
    }
    if (kt == 0) {  // new q-tile: load raw Q row, fused RMSNorm+RoPE+HEAD_SCALE
      const int qrow = j * 32 + rh * 16 + la;
      const _Float16* Qg = Q + ((size_t)(b * NS + qrow)) * ND + h * NHD + lq * 8;
      float xq[4][8];
      float ss = 0.f;
#pragma unroll
      for (int kc = 0; kc < 4; ++kc) {
        h8 v = *(const h8*)(Qg + kc * 32);
#pragma unroll
        for (int e = 0; e < 8; ++e) { xq[kc][e] = (float)v[e]; ss += xq[kc][e] * xq[kc][e]; }
      }
      ss += __shfl_xor(ss, 16, 64);
      ss += __shfl_xor(ss, 32, 64);
      float rn = rsqrtf(ss * (1.0f / 128.0f) + 1e-6f);
#pragma unroll
      for (int kc = 0; kc < 2; ++kc) {
        const float* s1p = qns + kc * 32 + lq * 8;
        const float* s2p = qns + (kc + 2) * 32 + lq * 8;
        const float* ctp = cosT + qrow * 64 + kc * 32 + lq * 8;
        const float* stp = sinT + qrow * 64 + kc * 32 + lq * 8;
        fx4 s1a = *(const fx4*)s1p, s1b = *(const fx4*)(s1p + 4);
        fx4 s2a = *(const fx4*)s2p, s2b = *(const fx4*)(s2p + 4);
        fx4 ca = *(const fx4*)ctp, cb2 = *(const fx4*)(ctp + 4);
        fx4 sa = *(const fx4*)stp, sb = *(const fx4*)(stp + 4);
#pragma unroll
        for (int e = 0; e < 8; ++e) {
          float sc1 = (e < 4) ? s1a[e & 3] : s1b[e & 3];
          float sc2 = (e < 4) ? s2a[e & 3] : s2b[e & 3];
          float cc = (e < 4) ? ca[e & 3] : cb2[e & 3];
          float sn = (e < 4) ? sa[e & 3] : sb[e & 3];
          float n1 = xq[kc][e] * rn * sc1;
          float n2 = xq[kc + 2][e] * rn * sc2;
          qf[kc][e] = (_Float16)((n1 * cc - n2 * sn) * HEAD_SCALE);
          qf[kc + 2][e] = (_Float16)((n1 * sn + n2 * cc) * HEAD_SCALE);
        }
      }
#pragma unroll
      for (int f = 0; f < 8; ++f) oacc[f] = fx4{0.f, 0.f, 0.f, 0.f};
#pragma unroll
      for (int r = 0; r < 4; ++r) { mrun[r] = -1e30f; lrun[r] = 0.f; }
    }

    // QK^T: 16 q-rows x 64 kv
    fx4 sc[4] = {};
    __builtin_amdgcn_s_setprio(1);
#pragma unroll
    for (int n = 0; n < 4; ++n) {
      int row = n * 16 + la;
#pragma unroll
      for (int kc = 0; kc < 4; ++kc) {
        h8 bk = *(const h8*)&Ks[cur][row * 128 + (((kc * 4 + lq) ^ (la & 7)) * 8)];
        sc[n] = __builtin_amdgcn_mfma_f32_16x16x32_f16(qf[kc], bk, sc[n], 0, 0, 0);
      }
    }
    __builtin_amdgcn_s_setprio(0);

    const int qrow0 = j * 32 + rh * 16 + lq * 4;
    const bool maskT = (kt == ntj - 1);
    float pv[4][4];
    float rm[4] = {-1e30f, -1e30f, -1e30f, -1e30f};
#pragma unroll
    for (int n = 0; n < 4; ++n) {
      int kv = kt * 64 + n * 16 + la;
#pragma unroll
      for (int r = 0; r < 4; ++r) {
        float sv = sc[n][r] * HEAD_SCALE;
        sv = (maskT && kv > qrow0 + r) ? -1e30f : sv;
        pv[n][r] = sv;
        rm[r] = fmaxf(rm[r], sv);
      }
    }
#pragma unroll
    for (int r = 0; r < 4; ++r)
#pragma unroll
      for (int m = 1; m < 16; m <<= 1) rm[r] = fmaxf(rm[r], __shfl_xor(rm[r], m, 64));
    // T13 defer-max: skip O-rescale when tile-max within 8 of running max.
    bool defer = (rm[0] - mrun[0] <= 8.f) && (rm[1] - mrun[1] <= 8.f) &&
                 (rm[2] - mrun[2] <= 8.f) && (rm[3] - mrun[3] <= 8.f);
    if (!__all(defer)) {
#pragma unroll
      for (int r = 0; r < 4; ++r) {
        float mn = fmaxf(mrun[r], rm[r]);
        float corr = __expf(mrun[r] - mn);
        mrun[r] = mn;
        lrun[r] *= corr;
#pragma unroll
        for (int f = 0; f < 8; ++f) oacc[f][r] *= corr;
      }
    }
    float rs[4] = {0.f, 0.f, 0.f, 0.f};
#pragma unroll
    for (int n = 0; n < 4; ++n)
#pragma unroll
      for (int r = 0; r < 4; ++r) {
        float e = __expf(pv[n][r] - mrun[r]);
        pv[n][r] = e;
        rs[r] += e;
      }
#pragma unroll
    for (int r = 0; r < 4; ++r) {
#pragma unroll
      for (int m = 1; m < 16; m <<= 1) rs[r] += __shfl_xor(rs[r], m, 64);
      lrun[r] += rs[r];
    }

    // P (C-layout) -> LDS (swizzled) -> reload in A-layout (wave-local)
#pragma unroll
    for (int n = 0; n < 4; ++n)
#pragma unroll
      for (int r = 0; r < 4; ++r) {
        int row = lq * 4 + r;
        int chsw = (n * 2 + (la >> 3)) ^ (row & 7);
        Ps[w][row * 64 + chsw * 8 + (la & 7)] = (_Float16)pv[n][r];
      }
    asm volatile("s_waitcnt lgkmcnt(0)" ::: "memory");
    __builtin_amdgcn_sched_barrier(0);
    h8 pf[2];
#pragma unroll
    for (int ks = 0; ks < 2; ++ks)
      pf[ks] = *(const h8*)&Ps[w][la * 64 + (((ks * 4 + lq) ^ (la & 7)) * 8)];

    // PV
    __builtin_amdgcn_s_setprio(1);
#pragma unroll
    for (int f = 0; f < 8; ++f) {
      int row = f * 16 + la;
#pragma unroll
      for (int ks = 0; ks < 2; ++ks) {
        h8 bv = *(const h8*)&Vs[cur][row * 64 + (((ks * 4 + lq) ^ (la & 7)) * 8)];
        oacc[f] = __builtin_amdgcn_mfma_f32_16x16x32_f16(pf[ks], bv, oacc[f], 0, 0, 0);
      }
    }
    __builtin_amdgcn_s_setprio(0);

    if (maskT) {  // last tile of this q-tile: direct store (r11-verified)
      _Float16* Cg = ctx + ((size_t)(b * NS + qrow0)) * ND + h * NHD + la;
      float inv_l[4];
#pragma unroll
      for (int r = 0; r < 4; ++r) inv_l[r] = 1.0f / lrun[r];
#pragma unroll
      for (int f = 0; f < 8; ++f)
#pragma unroll
        for (int r = 0; r < 4; ++r)
          Cg[(size_t)r * ND + f * 16] = (_Float16)(oacc[f][r] * inv_l[r]);
    }
    cur ^= 1;
  }
}

// ---------------- launch ----------------

extern "C" void kernel_launch(void* const* d_in, const int* in_sizes, int n_in,
                              void* d_out, int out_size, void* d_ws, size_t ws_size,
                              hipStream_t stream) {
  (void)in_sizes; (void)n_in; (void)out_size; (void)ws_size;
  const float* x = (const float*)d_in[0];
  const float* wq = (const float*)d_in[1];
  const float* bq = (const float*)d_in[2];
  const float* wk = (const float*)d_in[3];
  const float* bk = (const float*)d_in[4];
  const float* wv = (const float*)d_in[5];
  const float* bv = (const float*)d_in[6];
  const float* wo = (const float*)d_in[7];
  const float* bo = (const float*)d_in[8];
  const float* qns = (const float*)d_in[9];
  const float* kns = (const float*)d_in[10];

  char* ws = (char*)d_ws;
  size_t off = 0;
  _Float16* xh = (_Float16*)(ws + off); off += (size_t)NM * ND * 2;       // 32MB
  _Float16* wqt = (_Float16*)(ws + off); off += (size_t)ND * ND * 2;      // 8MB
  _Float16* wkvt = (_Float16*)(ws + off); off += (size_t)NKV * ND * 2;    // 4MB
  _Float16* wot = (_Float16*)(ws + off); off += (size_t)ND * ND * 2;      // 8MB
  _Float16* Qb = (_Float16*)(ws + off); off += (size_t)NM * ND * 2;       // 32MB
  _Float16* KVbuf = (_Float16*)(ws + off); off += (size_t)NM * NKV * 2;   // 16MB
  float* cosT = (float*)(ws + off); off += (size_t)NS * 64 * 4;
  float* sinT = (float*)(ws + off); off += (size_t)NS * 64 * 4;
  float* bkv = (float*)(ws + off); off += (size_t)NKV * 4;
  _Float16* ctx = xh;            // xh dead after KV GEMM; reuse
  _Float16* Vtg = wqt;           // wqt dead after Q GEMM; reuse

  prep_kernel<<<dim3(4737), 256, 0, stream>>>(x, xh, wq, wqt, wk, wv, wkvt, wo, wot,
                                              cosT, sinT, bk, bv, bkv);

  gemm256_kernel<_Float16><<<dim3(256), dim3(512), 0, stream>>>(xh, wqt, bq, Qb, ND, ND);
  gemm256n128_kernel<<<dim3(256), dim3(512), 0, stream>>>(xh, wkvt, bkv, KVbuf, NKV, ND);

  kv_post_kernel<<<dim3(9216), 256, 0, stream>>>(KVbuf, Vtg, kns, cosT, sinT);

  attn_kernel<<<dim3(512), dim3(512), 0, stream>>>(Qb, KVbuf, Vtg, ctx, qns, cosT, sinT);

  gemm256_kernel<float><<<dim3(256), dim3(512), 0, stream>>>(ctx, wot, bo, (float*)d_out, ND, ND);
}